// Round 1
// baseline (442.443 us; speedup 1.0000x reference)
//
#include <hip/hip_runtime.h>
#include <cstdint>
#include <cstddef>

typedef unsigned long long ull;

#define NA     147456   // 128*128*9 anchors
#define NT     64       // targets
#define KDIM   4608     // 512*9 reduction
#define NTASK  1280     // 128*6 + 256*2 output-value tasks
#define CAND_CAP 4096

// ---- workspace byte offsets (total ~3.26 MB; ws re-poisoned each call, k_zero re-inits) ----
#define OFF_H      0           // float[512*1280]  conv partial sums (atomic accum, zeroed)
#define OFF_MIOU   2621440     // float[147456]
#define OFF_CAND   3211264     // ull[4096]
#define OFF_CZ     3244032     // int[144] zero-iou counts per 1024-chunk (zeroed)
#define OFF_PCNT   3244608     // int (zeroed)
#define OFF_NPOS   3244612     // int
#define OFF_NEG    3244616     // int[256]
#define OFF_POSA   3245640     // int[128]
#define OFF_TREG   3246152     // float[512]
#define OFF_TASKS  3248200     // int[1280]
#define OFF_OUT    3253320     // float[1280]

// anchor w/h table; U = sqrt(128*128/2); power-of-2 multiples are exact in fp32,
// matching python float64 sqrt -> fp32 cast.
#define UANC 90.509667991878f
__device__ __constant__ float WKa[9] = {128.0f, 2.0f*UANC, UANC, 256.0f, 4.0f*UANC, 2.0f*UANC, 512.0f, 8.0f*UANC, 4.0f*UANC};
__device__ __constant__ float HKa[9] = {128.0f, UANC, 2.0f*UANC, 256.0f, 2.0f*UANC, 4.0f*UANC, 512.0f, 4.0f*UANC, 8.0f*UANC};

// IoU exactly as reference (no fp contraction so exact ties between anchors are preserved)
__device__ __forceinline__ float iou_one(float x1, float y1, float x2, float y2, float4 t) {
#pragma clang fp contract(off)
  float ltx = fmaxf(t.x, x1), lty = fmaxf(t.y, y1);
  float rbx = fminf(t.z, x2), rby = fminf(t.w, y2);
  float wx = fmaxf(rbx - ltx, 0.0f);
  float wy = fmaxf(rby - lty, 0.0f);
  float inter = wx * wy;
  float at = (t.z - t.x) * (t.w - t.y);
  float aa = (x2 - x1) * (y2 - y1);
  return inter / ((at + aa) - inter);
}

__global__ __launch_bounds__(256) void k_zero(float* __restrict__ H, int* __restrict__ zint) {
  int i = blockIdx.x * 256 + threadIdx.x;
  if (i < 512 * NTASK) H[i] = 0.0f;
  if (i < 146) zint[i] = 0;   // cz[144] + pcnt + npos
}

__global__ __launch_bounds__(256) void k_iou(const float* __restrict__ tgt,
    const int* __restrict__ imw, const int* __restrict__ imh,
    float* __restrict__ miou, ull* __restrict__ cand, int* __restrict__ pcnt,
    int* __restrict__ cz) {
  __shared__ float4 ts[NT];
  int tid = threadIdx.x;
  if (tid < NT) ts[tid] = ((const float4*)tgt)[tid];
  __syncthreads();
  int a = blockIdx.x * 256 + tid;              // grid exactly covers NA
  int k = a % 9;
  int pq = a / 9;
  int p = pq >> 7, q = pq & 127;
  float dx = (float)(*imw) / 127.0f;           // jnp.linspace step, fp32
  float dyl = (float)(*imh) / 127.0f;
  float x1 = (float)p * dx, y1 = (float)q * dyl;
  float x2 = x1 + WKa[k], y2 = y1 + HKa[k];
  float best = -1.0f;
  #pragma unroll 8
  for (int t = 0; t < NT; ++t) best = fmaxf(best, iou_one(x1, y1, x2, y2, ts[t]));
  miou[a] = best;
  bool z = (best == 0.0f);
  ull b = __ballot(z);
  if ((tid & 63) == 0) atomicAdd(&cz[a >> 10], (int)__popcll(b));
  if (best > 0.7f) {
    int i = atomicAdd(pcnt, 1);
    if (i < CAND_CAP)
      cand[i] = ((ull)__float_as_uint(best) << 32) | (ull)(0xFFFFFFFFu - (unsigned)a);
  }
}

// negs = 256 lowest-indexed anchors with max_iou == 0 (>=3456 exist by input ranges)
__global__ __launch_bounds__(256) void k_neg(const float* __restrict__ miou,
    const int* __restrict__ cz, int* __restrict__ neg) {
  __shared__ int base[145];
  __shared__ int wsum[4];
  int tid = threadIdx.x;
  if (tid == 0) {
    int s = 0;
    for (int j = 0; j < 144; ++j) { base[j] = s; s += cz[j]; }
    base[144] = s;
  }
  __syncthreads();
  int lane = tid & 63, w = tid >> 6;
  for (int j = 0; j < 144; ++j) {
    if (base[j] >= 256) break;                 // uniform
    int a0 = j * 1024 + tid * 4;
    float4 m4 = *(const float4*)(miou + a0);
    int f0 = (m4.x == 0.0f), f1 = (m4.y == 0.0f), f2 = (m4.z == 0.0f), f3 = (m4.w == 0.0f);
    int tsum = f0 + f1 + f2 + f3;
    int scan = tsum;
    for (int off = 1; off < 64; off <<= 1) {
      int v = __shfl_up(scan, off);
      if (lane >= off) scan += v;
    }
    if (lane == 63) wsum[w] = scan;
    __syncthreads();
    int woff = base[j];
    for (int i = 0; i < w; ++i) woff += wsum[i];
    int r = woff + scan - tsum;                // exclusive rank
    if (f0) { if (r < 256) neg[r] = a0;     r++; }
    if (f1) { if (r < 256) neg[r] = a0 + 1; r++; }
    if (f2) { if (r < 256) neg[r] = a0 + 2; r++; }
    if (f3) { if (r < 256) neg[r] = a0 + 3;      }
    __syncthreads();
  }
}

// exact top-128 of (iou desc, index asc) via bitonic sort of packed keys
__global__ __launch_bounds__(256) void k_psort(const ull* __restrict__ cand,
    const int* __restrict__ pcnt, int* __restrict__ posa, int* __restrict__ nposp) {
  __shared__ ull keys[CAND_CAP];
  int tid = threadIdx.x;
  int cnt = *pcnt; if (cnt > CAND_CAP) cnt = CAND_CAP;
  for (int i = tid; i < CAND_CAP; i += 256) keys[i] = (i < cnt) ? cand[i] : 0ull;
  for (int size = 2; size <= CAND_CAP; size <<= 1)
    for (int stride = size >> 1; stride > 0; stride >>= 1) {
      __syncthreads();
      for (int t = tid; t < CAND_CAP / 2; t += 256) {
        int i = 2 * t - (t & (stride - 1));
        int j = i + stride;
        ull a = keys[i], b = keys[j];
        bool desc = ((i & size) == 0);
        if (desc ? (a < b) : (a > b)) { keys[i] = b; keys[j] = a; }
      }
    }
  __syncthreads();
  int np = cnt < 128 ? cnt : 128;
  if (tid < np) posa[tid] = (int)(0xFFFFFFFFu - (unsigned)(keys[tid] & 0xFFFFFFFFull));
  if (tid == 0) *nposp = np;
}

// build task table (pixel,y,x,weight-row) + treg for pos anchors
__global__ __launch_bounds__(256) void k_tasks(const float* __restrict__ tgt,
    const int* __restrict__ imw, const int* __restrict__ imh,
    const int* __restrict__ nposp, const int* __restrict__ posa,
    const int* __restrict__ neg, float* __restrict__ treg, int* __restrict__ tasks) {
  __shared__ float4 ts[NT];
  int tid = threadIdx.x;
  if (tid < NT) ts[tid] = ((const float4*)tgt)[tid];
  __syncthreads();
  int np = *nposp;
  if (tid < np) {
    int a = posa[tid];
    int k = a % 9; int pq = a / 9; int p = pq >> 7, q = pq & 127;
    float dx = (float)(*imw) / 127.0f, dyl = (float)(*imh) / 127.0f;
    float x1 = (float)p * dx, y1 = (float)q * dyl;
    float x2 = x1 + WKa[k], y2 = y1 + HKa[k];
    float best = -1.0f; int bt = 0;
    for (int t = 0; t < NT; ++t) {
      float v = iou_one(x1, y1, x2, y2, ts[t]);
      if (v > best) { best = v; bt = t; }      // first-max == jnp.argmax
    }
    float4 m = ts[bt];
    float aw = x2 - x1, ah = y2 - y1;
    float acx = x1 + aw * 0.5f, acy = y1 + ah * 0.5f;
    float bwd = m.z - m.x, bhd = m.w - m.y;
    float bcx = m.x + bwd * 0.5f, bcy = m.y + bhd * 0.5f;
    treg[tid * 4 + 0] = (bcx - acx) / aw;
    treg[tid * 4 + 1] = (bcy - acy) / ah;
    treg[tid * 4 + 2] = logf(bwd / aw);
    treg[tid * 4 + 3] = logf(bhd / ah);
  }
  for (int t = tid; t < NTASK; t += 256) {
    int rec = 0;
    if (t < 768) {
      int s = t / 6, jj = t - s * 6;
      if (s < np) {
        int a = posa[s];
        int f, wr, xx;
        if (jj < 4) { f = 4 * a; wr = f >> 14; xx = (f & 127) + jj; }          // bbox row
        else        { f = 2 * a; wr = 36 + (f >> 14); xx = (f & 127) + (jj - 4); } // score row
        int yy = (f >> 7) & 127;
        rec = (int)(0x80000000u | ((unsigned)wr << 16) | ((unsigned)yy << 8) | (unsigned)xx);
      }
    } else {
      int s = (t - 768) >> 1, jj = (t - 768) & 1;
      if (s < 256 - np) {
        int a = neg[s];
        int f = 2 * a; int wr = 36 + (f >> 14); int yy = (f >> 7) & 127; int xx = (f & 127) + jj;
        rec = (int)(0x80000000u | ((unsigned)wr << 16) | ((unsigned)yy << 8) | (unsigned)xx);
      }
    }
    tasks[t] = rec;
  }
}

// selective conv as fused-im2col fp32 GEMM: H[cout, task] += W[cout, k] * patch[k, task]
#define KC 32
#define CT 64
#define TT 128
#define KSPLIT 8
#define KPB 576
#define NCHUNK 18

__global__ __launch_bounds__(256) void k_gemm(
    const float* __restrict__ x, const float* __restrict__ cw,
    const int* __restrict__ tasks, const int* __restrict__ nposp,
    float* __restrict__ H) {
  __shared__ float wsm[CT][36];
  __shared__ float xsm[KC][132];
  __shared__ int trec[TT];
  const int tid = threadIdx.x;
  const int npos = *nposp;
  const int tt0 = blockIdx.x * TT;
  const int posend = 6 * npos;
  const int negend = 768 + 2 * (256 - npos);
  bool anyv = (tt0 < posend) || ((tt0 + TT > 768) && (tt0 < negend));
  if (!anyv) return;
  if (tid < TT) trec[tid] = tasks[tt0 + tid];
  __syncthreads();

  const int c0 = blockIdx.y * CT;
  const int kb = blockIdx.z * KPB;
  const int tx = tid & 15, ty = tid >> 4;
  const int wc = tid >> 2;
  const int wk = (tid & 3) * 8;
  const int xt = tid & 127;
  const int xh = tid >> 7;
  const int xrec = trec[xt];
  const bool xval = xrec < 0;
  const int py = (xrec >> 8) & 127;
  const int px = xrec & 127;

  bool tval[8];
  #pragma unroll
  for (int j = 0; j < 8; ++j) tval[j] = trec[tx * 8 + j] < 0;

  float acc[4][8];
  #pragma unroll
  for (int i = 0; i < 4; ++i)
    #pragma unroll
    for (int j = 0; j < 8; ++j) acc[i][j] = 0.0f;

  const float* wbase = cw + (size_t)(c0 + wc) * KDIM + wk;

  for (int ch = 0; ch < NCHUNK; ++ch) {
    const int k0 = kb + ch * KC;
    float4 wv0 = *(const float4*)(wbase + k0);
    float4 wv1 = *(const float4*)(wbase + k0 + 4);
    float xv[16];
    const int kk0 = k0 + xh * 16;
    #pragma unroll
    for (int u = 0; u < 16; ++u) {
      float v = 0.0f;
      if (xval) {
        int kk = kk0 + u;
        int cin = kk / 9;
        int r = kk - cin * 9;
        int yy = py + (r / 3) - 1;
        int xx = px + (r % 3) - 1;
        if (yy >= 0 && yy < 128 && xx >= 0 && xx < 128)
          v = x[cin * 16384 + yy * 128 + xx];
      }
      xv[u] = v;
    }
    __syncthreads();
    *(float4*)&wsm[wc][wk]     = wv0;
    *(float4*)&wsm[wc][wk + 4] = wv1;
    #pragma unroll
    for (int u = 0; u < 16; ++u) xsm[xh * 16 + u][xt] = xv[u];
    __syncthreads();
    #pragma unroll 8
    for (int k = 0; k < KC; ++k) {
      float w0 = wsm[ty * 4 + 0][k], w1 = wsm[ty * 4 + 1][k];
      float w2 = wsm[ty * 4 + 2][k], w3 = wsm[ty * 4 + 3][k];
      float4 xa = *(const float4*)&xsm[k][tx * 8];
      float4 xb = *(const float4*)&xsm[k][tx * 8 + 4];
      float xvv[8] = {xa.x, xa.y, xa.z, xa.w, xb.x, xb.y, xb.z, xb.w};
      #pragma unroll
      for (int j = 0; j < 8; ++j) {
        acc[0][j] = fmaf(w0, xvv[j], acc[0][j]);
        acc[1][j] = fmaf(w1, xvv[j], acc[1][j]);
        acc[2][j] = fmaf(w2, xvv[j], acc[2][j]);
        acc[3][j] = fmaf(w3, xvv[j], acc[3][j]);
      }
    }
  }
  #pragma unroll
  for (int i = 0; i < 4; ++i) {
    float* hrow = H + (size_t)(c0 + ty * 4 + i) * NTASK + tt0 + tx * 8;
    #pragma unroll
    for (int j = 0; j < 8; ++j)
      if (tval[j]) atomicAdd(hrow + j, acc[i][j]);
  }
}

// epilogue: relu(conv + conv_b) dot 1x1-row, + head bias, relu
__global__ __launch_bounds__(64) void k_out(const float* __restrict__ H,
    const int* __restrict__ tasks,
    const float* __restrict__ cb, const float* __restrict__ bw,
    const float* __restrict__ bb, const float* __restrict__ sw,
    const float* __restrict__ sb, float* __restrict__ outv) {
  int t = blockIdx.x;
  int rec = tasks[t];
  if (rec >= 0) return;
  int wr = (rec >> 16) & 63;
  int lane = threadIdx.x;
  const float* wrow = (wr < 36) ? (bw + wr * 512) : (sw + (wr - 36) * 512);
  float s = 0.0f;
  #pragma unroll
  for (int it = 0; it < 8; ++it) {
    int c = it * 64 + lane;
    float hv = H[(size_t)c * NTASK + t] + cb[c];
    s = fmaf(fmaxf(hv, 0.0f), wrow[c], s);
  }
  #pragma unroll
  for (int off = 32; off > 0; off >>= 1) s += __shfl_down(s, off);
  if (lane == 0) {
    float b = (wr < 36) ? bb[wr] : sb[wr - 36];
    outv[t] = fmaxf(s + b, 0.0f);
  }
}

__global__ __launch_bounds__(256) void k_loss(const float* __restrict__ outv,
    const float* __restrict__ treg, const int* __restrict__ nposp,
    float* __restrict__ out) {
  __shared__ float r1[256], r2[256];
  int tid = threadIdx.x;
  int np = *nposp;
  float ce = 0.0f;
  for (int r = tid; r < 384; r += 256) {
    bool valid = (r < 128) ? (r < np) : ((r - 128) < 256 - np);
    if (valid) {
      int t0 = (r < 128) ? (r * 6 + 4) : (768 + 2 * (r - 128));
      float s0 = outv[t0], s1 = outv[t0 + 1];
      float mm = fmaxf(s0, s1);
      float lse = mm + logf(expf(s0 - mm) + expf(s1 - mm));
      ce += lse - ((r < 128) ? s0 : s1);
    }
  }
  float rg = 0.0f;
  for (int r = tid; r < 512; r += 256) {
    if ((r >> 2) < np) {
      float d = outv[(r >> 2) * 6 + (r & 3)] - treg[r];
      float ad = fabsf(d);
      rg += (ad < 1.0f) ? 0.5f * d * d : ad - 0.5f;
    }
  }
  r1[tid] = ce; r2[tid] = rg;
  __syncthreads();
  for (int s = 128; s > 0; s >>= 1) {
    if (tid < s) { r1[tid] += r1[tid + s]; r2[tid] += r2[tid + s]; }
    __syncthreads();
  }
  if (tid == 0) {
    float score_loss = r1[0] / 256.0f;                       // sum(valid) == 256 always
    float reg_loss = r2[0] / fmaxf(4.0f * (float)np, 1.0f);
    out[0] = score_loss + 10.0f * reg_loss;
  }
}

extern "C" void kernel_launch(void* const* d_in, const int* in_sizes, int n_in,
                              void* d_out, int out_size, void* d_ws, size_t ws_size,
                              hipStream_t stream) {
  const float* x   = (const float*)d_in[0];
  const float* tgt = (const float*)d_in[1];
  const float* cw  = (const float*)d_in[2];
  const float* cb  = (const float*)d_in[3];
  const float* bw  = (const float*)d_in[4];
  const float* bb  = (const float*)d_in[5];
  const float* sw  = (const float*)d_in[6];
  const float* sb  = (const float*)d_in[7];
  const int* imh   = (const int*)d_in[8];
  const int* imw   = (const int*)d_in[9];

  char* ws = (char*)d_ws;
  float* H     = (float*)(ws + OFF_H);
  float* miou  = (float*)(ws + OFF_MIOU);
  ull*   cand  = (ull*)(ws + OFF_CAND);
  int*   cz    = (int*)(ws + OFF_CZ);
  int*   pcnt  = (int*)(ws + OFF_PCNT);
  int*   nposp = (int*)(ws + OFF_NPOS);
  int*   neg   = (int*)(ws + OFF_NEG);
  int*   posa  = (int*)(ws + OFF_POSA);
  float* treg  = (float*)(ws + OFF_TREG);
  int*   tasks = (int*)(ws + OFF_TASKS);
  float* outv  = (float*)(ws + OFF_OUT);
  float* out   = (float*)d_out;

  k_zero <<<dim3(2560),     dim3(256), 0, stream>>>(H, cz);
  k_iou  <<<dim3(NA / 256), dim3(256), 0, stream>>>(tgt, imw, imh, miou, cand, pcnt, cz);
  k_neg  <<<dim3(1),        dim3(256), 0, stream>>>(miou, cz, neg);
  k_psort<<<dim3(1),        dim3(256), 0, stream>>>(cand, pcnt, posa, nposp);
  k_tasks<<<dim3(1),        dim3(256), 0, stream>>>(tgt, imw, imh, nposp, posa, neg, treg, tasks);
  k_gemm <<<dim3(10, 8, KSPLIT), dim3(256), 0, stream>>>(x, cw, tasks, nposp, H);
  k_out  <<<dim3(NTASK),    dim3(64),  0, stream>>>(H, tasks, cb, bw, bb, sw, sb, outv);
  k_loss <<<dim3(1),        dim3(256), 0, stream>>>(outv, treg, nposp, out);
}

// Round 2
// 191.556 us; speedup vs baseline: 2.3097x; 2.3097x over previous
//
#include <hip/hip_runtime.h>
#include <cstdint>
#include <cstddef>

typedef unsigned long long ull;
typedef __bf16 bf16x8 __attribute__((ext_vector_type(8)));
typedef float f32x4 __attribute__((ext_vector_type(4)));

#define NA     147456   // 128*128*9 anchors
#define NT     64       // targets
#define KDIM   4608     // 512*9 reduction
#define NTASK  1280     // 128*6 + 256*2 output-value tasks
#define CAND_CAP 4096
#define KSPLIT 4

// ---- workspace byte offsets (total ~26.4 MB) ----
#define OFF_WB2   0           // ushort[576*512*8]  bf16 weights, fragment-native [kc][m][8]
#define OFF_P2    4718592     // ushort[576*1280*8] bf16 im2col,  fragment-native [kc][t][8]
#define OFF_H4    16515072    // float[4][1280][512] K-split partial h, task-major
#define OFF_MIOU  27000832    // float[147456]
#define OFF_CAND  27590656    // ull[4096]
#define OFF_CZ    27623424    // int[144]
#define OFF_PCNT  27624000    // int
#define OFF_NPOS  27624004    // int
#define OFF_NEG   27624008    // int[256]
#define OFF_POSA  27625032    // int[128]
#define OFF_TREG  27625544    // float[512]
#define OFF_TASKS 27627592    // int[1280]
#define OFF_OUT   27632712    // float[1280]

// anchor w/h table; U = sqrt(128*128/2); power-of-2 multiples are exact in fp32.
#define UANC 90.509667991878f
__device__ __constant__ float WKa[9] = {128.0f, 2.0f*UANC, UANC, 256.0f, 4.0f*UANC, 2.0f*UANC, 512.0f, 8.0f*UANC, 4.0f*UANC};
__device__ __constant__ float HKa[9] = {128.0f, UANC, 2.0f*UANC, 256.0f, 2.0f*UANC, 4.0f*UANC, 512.0f, 4.0f*UANC, 8.0f*UANC};

__device__ __forceinline__ float iou_one(float x1, float y1, float x2, float y2, float4 t) {
#pragma clang fp contract(off)
  float ltx = fmaxf(t.x, x1), lty = fmaxf(t.y, y1);
  float rbx = fminf(t.z, x2), rby = fminf(t.w, y2);
  float wx = fmaxf(rbx - ltx, 0.0f);
  float wy = fmaxf(rby - lty, 0.0f);
  float inter = wx * wy;
  float at = (t.z - t.x) * (t.w - t.y);
  float aa = (x2 - x1) * (y2 - y1);
  return inter / ((at + aa) - inter);
}

__device__ __forceinline__ unsigned short f2bf(float f) {
  unsigned int u = __float_as_uint(f);
  unsigned int r = (u + 0x7fffu + ((u >> 16) & 1u)) >> 16;
  return (unsigned short)r;
}

__global__ __launch_bounds__(256) void k_zero(int* __restrict__ zint) {
  int i = threadIdx.x;
  if (i < 145) zint[i] = 0;   // cz[144] + pcnt
}

// repack conv weights fp32 -> bf16 fragment-native: Wb2[kc][m][8], kc = k>>3
__global__ __launch_bounds__(256) void k_prep(const float* __restrict__ cw,
    unsigned short* __restrict__ Wb2) {
  int idx = blockIdx.x * 256 + threadIdx.x;    // 576*512 = 294912; kc = idx>>9, m = idx&511
  int m = idx & 511, kc = idx >> 9;
  const float4* src = (const float4*)(cw + (size_t)m * KDIM + kc * 8);
  float4 v0 = src[0], v1 = src[1];
  unsigned short o[8] = {f2bf(v0.x), f2bf(v0.y), f2bf(v0.z), f2bf(v0.w),
                         f2bf(v1.x), f2bf(v1.y), f2bf(v1.z), f2bf(v1.w)};
  *(uint4*)(Wb2 + (size_t)idx * 8) = *(const uint4*)o;   // (kc*512+m)*8 == idx*8
}

__global__ __launch_bounds__(256) void k_iou(const float* __restrict__ tgt,
    const int* __restrict__ imw, const int* __restrict__ imh,
    float* __restrict__ miou, ull* __restrict__ cand, int* __restrict__ pcnt,
    int* __restrict__ cz) {
  __shared__ float4 ts[NT];
  int tid = threadIdx.x;
  if (tid < NT) ts[tid] = ((const float4*)tgt)[tid];
  __syncthreads();
  int a = blockIdx.x * 256 + tid;
  int k = a % 9;
  int pq = a / 9;
  int p = pq >> 7, q = pq & 127;
  float dx = (float)(*imw) / 127.0f;
  float dyl = (float)(*imh) / 127.0f;
  float x1 = (float)p * dx, y1 = (float)q * dyl;
  float x2 = x1 + WKa[k], y2 = y1 + HKa[k];
  float best = -1.0f;
  #pragma unroll 8
  for (int t = 0; t < NT; ++t) best = fmaxf(best, iou_one(x1, y1, x2, y2, ts[t]));
  miou[a] = best;
  bool z = (best == 0.0f);
  ull b = __ballot(z);
  if ((tid & 63) == 0) atomicAdd(&cz[a >> 10], (int)__popcll(b));
  if (best > 0.7f) {
    int i = atomicAdd(pcnt, 1);
    if (i < CAND_CAP)
      cand[i] = ((ull)__float_as_uint(best) << 32) | (ull)(0xFFFFFFFFu - (unsigned)a);
  }
}

// negs = first 256 zero-iou anchors by index (>=3456 exist by input ranges)
__global__ __launch_bounds__(256) void k_neg(const float* __restrict__ miou,
    const int* __restrict__ cz, int* __restrict__ neg) {
  __shared__ int base[145];
  __shared__ int wsum[4];
  int tid = threadIdx.x;
  if (tid == 0) {
    int s = 0;
    for (int j = 0; j < 144; ++j) { base[j] = s; s += cz[j]; }
    base[144] = s;
  }
  __syncthreads();
  int lane = tid & 63, w = tid >> 6;
  for (int j = 0; j < 144; ++j) {
    if (base[j] >= 256) break;
    int a0 = j * 1024 + tid * 4;
    float4 m4 = *(const float4*)(miou + a0);
    int f0 = (m4.x == 0.0f), f1 = (m4.y == 0.0f), f2 = (m4.z == 0.0f), f3 = (m4.w == 0.0f);
    int tsum = f0 + f1 + f2 + f3;
    int scan = tsum;
    for (int off = 1; off < 64; off <<= 1) {
      int v = __shfl_up(scan, off);
      if (lane >= off) scan += v;
    }
    if (lane == 63) wsum[w] = scan;
    __syncthreads();
    int woff = base[j];
    for (int i = 0; i < w; ++i) woff += wsum[i];
    int r = woff + scan - tsum;
    if (f0) { if (r < 256) neg[r] = a0;     r++; }
    if (f1) { if (r < 256) neg[r] = a0 + 1; r++; }
    if (f2) { if (r < 256) neg[r] = a0 + 2; r++; }
    if (f3) { if (r < 256) neg[r] = a0 + 3;      }
    __syncthreads();
  }
}

// top-128 SET of (iou desc, idx asc). Slot order is irrelevant to the loss
// (all per-slot contributions are summed, pairing is slot-consistent), so:
// cnt<=128 -> take all, no sort. Else bitonic over next-pow2(cnt).
__global__ __launch_bounds__(256) void k_psort(const ull* __restrict__ cand,
    const int* __restrict__ pcnt, int* __restrict__ posa, int* __restrict__ nposp) {
  __shared__ ull keys[CAND_CAP];
  int tid = threadIdx.x;
  int cnt = *pcnt; if (cnt > CAND_CAP) cnt = CAND_CAP;
  if (cnt <= 128) {
    if (tid < cnt) posa[tid] = (int)(0xFFFFFFFFu - (unsigned)(cand[tid] & 0xFFFFFFFFull));
    if (tid == 0) *nposp = cnt;
    return;
  }
  int n = 256; while (n < cnt) n <<= 1;
  for (int i = tid; i < n; i += 256) keys[i] = (i < cnt) ? cand[i] : 0ull;
  for (int size = 2; size <= n; size <<= 1)
    for (int stride = size >> 1; stride > 0; stride >>= 1) {
      __syncthreads();
      for (int t = tid; t < n / 2; t += 256) {
        int i = 2 * t - (t & (stride - 1));
        int j = i + stride;
        ull a = keys[i], b = keys[j];
        bool desc = ((i & size) == 0);
        if (desc ? (a < b) : (a > b)) { keys[i] = b; keys[j] = a; }
      }
    }
  __syncthreads();
  if (tid < 128) posa[tid] = (int)(0xFFFFFFFFu - (unsigned)(keys[tid] & 0xFFFFFFFFull));
  if (tid == 0) *nposp = 128;
}

// build task table (weight-row, pixel) + treg for pos anchors
__global__ __launch_bounds__(256) void k_tasks(const float* __restrict__ tgt,
    const int* __restrict__ imw, const int* __restrict__ imh,
    const int* __restrict__ nposp, const int* __restrict__ posa,
    const int* __restrict__ neg, float* __restrict__ treg, int* __restrict__ tasks) {
  __shared__ float4 ts[NT];
  int tid = threadIdx.x;
  if (tid < NT) ts[tid] = ((const float4*)tgt)[tid];
  __syncthreads();
  int np = *nposp;
  if (tid < np) {
    int a = posa[tid];
    int k = a % 9; int pq = a / 9; int p = pq >> 7, q = pq & 127;
    float dx = (float)(*imw) / 127.0f, dyl = (float)(*imh) / 127.0f;
    float x1 = (float)p * dx, y1 = (float)q * dyl;
    float x2 = x1 + WKa[k], y2 = y1 + HKa[k];
    float best = -1.0f; int bt = 0;
    for (int t = 0; t < NT; ++t) {
      float v = iou_one(x1, y1, x2, y2, ts[t]);
      if (v > best) { best = v; bt = t; }
    }
    float4 m = ts[bt];
    float aw = x2 - x1, ah = y2 - y1;
    float acx = x1 + aw * 0.5f, acy = y1 + ah * 0.5f;
    float bwd = m.z - m.x, bhd = m.w - m.y;
    float bcx = m.x + bwd * 0.5f, bcy = m.y + bhd * 0.5f;
    treg[tid * 4 + 0] = (bcx - acx) / aw;
    treg[tid * 4 + 1] = (bcy - acy) / ah;
    treg[tid * 4 + 2] = logf(bwd / aw);
    treg[tid * 4 + 3] = logf(bhd / ah);
  }
  for (int t = tid; t < NTASK; t += 256) {
    int rec = 0;
    if (t < 768) {
      int s = t / 6, jj = t - s * 6;
      if (s < np) {
        int a = posa[s];
        int f, wr, xx;
        if (jj < 4) { f = 4 * a; wr = f >> 14; xx = (f & 127) + jj; }
        else        { f = 2 * a; wr = 36 + (f >> 14); xx = (f & 127) + (jj - 4); }
        int yy = (f >> 7) & 127;
        rec = (int)(0x80000000u | ((unsigned)wr << 16) | ((unsigned)yy << 8) | (unsigned)xx);
      }
    } else {
      int s = (t - 768) >> 1, jj = (t - 768) & 1;
      if (s < 256 - np) {
        int a = neg[s];
        int f = 2 * a; int wr = 36 + (f >> 14); int yy = (f >> 7) & 127; int xx = (f & 127) + jj;
        rec = (int)(0x80000000u | ((unsigned)wr << 16) | ((unsigned)yy << 8) | (unsigned)xx);
      }
    }
    tasks[t] = rec;
  }
}

// im2col, fragment-native bf16: P2[kc][t][8]; invalid tasks zero-filled
__global__ __launch_bounds__(256) void k_im2col(const float* __restrict__ x,
    const int* __restrict__ tasks, unsigned short* __restrict__ P2) {
  int idx = blockIdx.x * 256 + threadIdx.x;    // 576*1280 = 737280; kc = idx/1280, t inner
  int t = idx % NTASK;
  int kc = idx / NTASK;
  int rec = tasks[t];
  unsigned short o[8];
  if (rec < 0) {
    int py = (rec >> 8) & 127, px = rec & 127;
    #pragma unroll
    for (int j = 0; j < 8; ++j) {
      int k = kc * 8 + j;
      int cin = k / 9;
      int rr = k - cin * 9;
      int dy = rr / 3;
      int yy = py + dy - 1, xx = px + (rr - dy * 3) - 1;
      float v = (yy >= 0 && yy < 128 && xx >= 0 && xx < 128)
                  ? x[cin * 16384 + yy * 128 + xx] : 0.0f;
      o[j] = f2bf(v);
    }
  } else {
    #pragma unroll
    for (int j = 0; j < 8; ++j) o[j] = 0;
  }
  *(uint4*)(P2 + (size_t)idx * 8) = *(const uint4*)o;    // (kc*1280+t)*8 == idx*8
}

// LDS-free bf16 MFMA GEMM. Block 256thr = 4 waves (2x2), wave tile 64x64,
// block tile 128 cout x 128 task. grid (10 ttile, 4 ctile, KSPLIT).
// Verified 16x16x32 layouts: A[m=lane&15][k=quad*8+j], B[k=quad*8+j][n=lane&15],
// D: n=lane&15, m=quad*4+reg. Fragment-native operands make loads coalesced.
__global__ __launch_bounds__(256) void k_mfma(const unsigned short* __restrict__ Wb2,
    const unsigned short* __restrict__ P2, const int* __restrict__ nposp,
    float* __restrict__ H4) {
  int npos = *nposp;
  int tt0 = blockIdx.x * 128;
  int posend = 6 * npos, negend = 768 + 2 * (256 - npos);
  if (!((tt0 < posend) || ((tt0 + 128 > 768) && (tt0 < negend)))) return;
  int c0 = blockIdx.y * 128;
  int ks = blockIdx.z;
  int tid = threadIdx.x;
  int wave = tid >> 6, lane = tid & 63;
  int quad = lane >> 4, r = lane & 15;
  int m_base = c0 + (wave & 1) * 64;
  int n_base = tt0 + (wave >> 1) * 64;
  int kc0 = ks * 144 + quad;                  // 144 k-chunks per split; step covers 4
  const bf16x8* Ab = (const bf16x8*)Wb2 + ((size_t)kc0 * 512 + m_base + r);
  const bf16x8* Bb = (const bf16x8*)P2 + ((size_t)kc0 * NTASK + n_base + r);

  f32x4 acc[4][4];
  #pragma unroll
  for (int i = 0; i < 4; ++i)
    #pragma unroll
    for (int j = 0; j < 4; ++j) acc[i][j] = (f32x4){0.f, 0.f, 0.f, 0.f};

  bf16x8 a[4], b[4];
  #pragma unroll
  for (int mi = 0; mi < 4; ++mi) a[mi] = Ab[mi * 16];
  #pragma unroll
  for (int ni = 0; ni < 4; ++ni) b[ni] = Bb[ni * 16];

  for (int s = 0; s < 36; ++s) {
    bf16x8 an[4], bn[4];
    if (s < 35) {
      const bf16x8* An = Ab + (size_t)(s + 1) * 4 * 512;
      const bf16x8* Bn = Bb + (size_t)(s + 1) * 4 * NTASK;
      #pragma unroll
      for (int mi = 0; mi < 4; ++mi) an[mi] = An[mi * 16];
      #pragma unroll
      for (int ni = 0; ni < 4; ++ni) bn[ni] = Bn[ni * 16];
    }
    #pragma unroll
    for (int mi = 0; mi < 4; ++mi)
      #pragma unroll
      for (int ni = 0; ni < 4; ++ni)
        acc[mi][ni] = __builtin_amdgcn_mfma_f32_16x16x32_bf16(a[mi], b[ni], acc[mi][ni], 0, 0, 0);
    if (s < 35) {
      #pragma unroll
      for (int mi = 0; mi < 4; ++mi) a[mi] = an[mi];
      #pragma unroll
      for (int ni = 0; ni < 4; ++ni) b[ni] = bn[ni];
    }
  }
  // store: H4[ks][t][c], c consecutive over reg -> float4 stores
  size_t hb = (size_t)ks * NTASK;
  #pragma unroll
  for (int mi = 0; mi < 4; ++mi) {
    int c = m_base + mi * 16 + quad * 4;
    #pragma unroll
    for (int ni = 0; ni < 4; ++ni) {
      int t = n_base + ni * 16 + r;
      *(f32x4*)(H4 + (hb + t) * 512 + c) = acc[mi][ni];
    }
  }
}

// epilogue: sum K-split slices, +conv_b, relu, dot head row, +bias, relu
__global__ __launch_bounds__(64) void k_out(const float* __restrict__ H4,
    const int* __restrict__ tasks,
    const float* __restrict__ cb, const float* __restrict__ bw,
    const float* __restrict__ bb, const float* __restrict__ sw,
    const float* __restrict__ sb, float* __restrict__ outv) {
  int t = blockIdx.x;
  int rec = tasks[t];
  if (rec >= 0) return;
  int wr = (rec >> 16) & 63;
  int lane = threadIdx.x;
  const float* wrow = (wr < 36) ? (bw + wr * 512) : (sw + (wr - 36) * 512);
  float s = 0.0f;
  #pragma unroll
  for (int it = 0; it < 8; ++it) {
    int c = it * 64 + lane;
    size_t o = (size_t)t * 512 + c;
    float hv = H4[o] + H4[o + 1280 * 512] + H4[o + 2 * 1280 * 512] + H4[o + 3 * 1280 * 512] + cb[c];
    s = fmaf(fmaxf(hv, 0.0f), wrow[c], s);
  }
  #pragma unroll
  for (int off = 32; off > 0; off >>= 1) s += __shfl_down(s, off);
  if (lane == 0) {
    float b = (wr < 36) ? bb[wr] : sb[wr - 36];
    outv[t] = fmaxf(s + b, 0.0f);
  }
}

__global__ __launch_bounds__(256) void k_loss(const float* __restrict__ outv,
    const float* __restrict__ treg, const int* __restrict__ nposp,
    float* __restrict__ out) {
  __shared__ float r1[256], r2[256];
  int tid = threadIdx.x;
  int np = *nposp;
  float ce = 0.0f;
  for (int r = tid; r < 384; r += 256) {
    bool valid = (r < 128) ? (r < np) : ((r - 128) < 256 - np);
    if (valid) {
      int t0 = (r < 128) ? (r * 6 + 4) : (768 + 2 * (r - 128));
      float s0 = outv[t0], s1 = outv[t0 + 1];
      float mm = fmaxf(s0, s1);
      float lse = mm + logf(expf(s0 - mm) + expf(s1 - mm));
      ce += lse - ((r < 128) ? s0 : s1);
    }
  }
  float rg = 0.0f;
  for (int r = tid; r < 512; r += 256) {
    if ((r >> 2) < np) {
      float d = outv[(r >> 2) * 6 + (r & 3)] - treg[r];
      float ad = fabsf(d);
      rg += (ad < 1.0f) ? 0.5f * d * d : ad - 0.5f;
    }
  }
  r1[tid] = ce; r2[tid] = rg;
  __syncthreads();
  for (int s = 128; s > 0; s >>= 1) {
    if (tid < s) { r1[tid] += r1[tid + s]; r2[tid] += r2[tid + s]; }
    __syncthreads();
  }
  if (tid == 0) {
    float score_loss = r1[0] / 256.0f;
    float reg_loss = r2[0] / fmaxf(4.0f * (float)np, 1.0f);
    out[0] = score_loss + 10.0f * reg_loss;
  }
}

extern "C" void kernel_launch(void* const* d_in, const int* in_sizes, int n_in,
                              void* d_out, int out_size, void* d_ws, size_t ws_size,
                              hipStream_t stream) {
  const float* x   = (const float*)d_in[0];
  const float* tgt = (const float*)d_in[1];
  const float* cw  = (const float*)d_in[2];
  const float* cb  = (const float*)d_in[3];
  const float* bw  = (const float*)d_in[4];
  const float* bb  = (const float*)d_in[5];
  const float* sw  = (const float*)d_in[6];
  const float* sb  = (const float*)d_in[7];
  const int* imh   = (const int*)d_in[8];
  const int* imw   = (const int*)d_in[9];

  char* ws = (char*)d_ws;
  unsigned short* Wb2 = (unsigned short*)(ws + OFF_WB2);
  unsigned short* P2  = (unsigned short*)(ws + OFF_P2);
  float* H4    = (float*)(ws + OFF_H4);
  float* miou  = (float*)(ws + OFF_MIOU);
  ull*   cand  = (ull*)(ws + OFF_CAND);
  int*   cz    = (int*)(ws + OFF_CZ);
  int*   pcnt  = (int*)(ws + OFF_PCNT);
  int*   nposp = (int*)(ws + OFF_NPOS);
  int*   neg   = (int*)(ws + OFF_NEG);
  int*   posa  = (int*)(ws + OFF_POSA);
  float* treg  = (float*)(ws + OFF_TREG);
  int*   tasks = (int*)(ws + OFF_TASKS);
  float* outv  = (float*)(ws + OFF_OUT);
  float* out   = (float*)d_out;

  k_zero  <<<dim3(1),        dim3(256), 0, stream>>>(cz);
  k_prep  <<<dim3(1152),     dim3(256), 0, stream>>>(cw, Wb2);
  k_iou   <<<dim3(NA / 256), dim3(256), 0, stream>>>(tgt, imw, imh, miou, cand, pcnt, cz);
  k_neg   <<<dim3(1),        dim3(256), 0, stream>>>(miou, cz, neg);
  k_psort <<<dim3(1),        dim3(256), 0, stream>>>(cand, pcnt, posa, nposp);
  k_tasks <<<dim3(1),        dim3(256), 0, stream>>>(tgt, imw, imh, nposp, posa, neg, treg, tasks);
  k_im2col<<<dim3(2880),     dim3(256), 0, stream>>>(x, tasks, P2);
  k_mfma  <<<dim3(10, 4, KSPLIT), dim3(256), 0, stream>>>(Wb2, P2, nposp, H4);
  k_out   <<<dim3(NTASK),    dim3(64),  0, stream>>>(H4, tasks, cb, bw, bb, sw, sb, outv);
  k_loss  <<<dim3(1),        dim3(256), 0, stream>>>(outv, treg, nposp, out);
}